// Round 13
// baseline (1407.980 us; speedup 1.0000x reference)
//
#include <hip/hip_runtime.h>
#include <cstdint>
#include <cstddef>

// ---------------------------------------------------------------- types
typedef __bf16 bf16x8 __attribute__((ext_vector_type(8)));
typedef __bf16 bf16x4 __attribute__((ext_vector_type(4)));
typedef float  f32x4  __attribute__((ext_vector_type(4)));

#define BATCH 2
#define SEQ   2048
#define DMODEL 2048
#define NHQ   16
#define NHKV  8
#define HDIM  128
#define FFDIM 8192
#define NTOK  4096          // BATCH*SEQ

__device__ __forceinline__ f32x4 mfma16(bf16x8 a, bf16x8 b, f32x4 c) {
    return __builtin_amdgcn_mfma_f32_16x16x32_bf16(a, b, c, 0, 0, 0);
}

__device__ __forceinline__ void gload16(const __bf16* g, __bf16* l) {
    __builtin_amdgcn_global_load_lds(
        (const __attribute__((address_space(1))) void*)g,
        (__attribute__((address_space(3))) void*)l, 16, 0, 0);
}

__device__ inline float wave_sum64(float v) {
    v += __shfl_xor(v, 1);  v += __shfl_xor(v, 2);  v += __shfl_xor(v, 4);
    v += __shfl_xor(v, 8);  v += __shfl_xor(v, 16); v += __shfl_xor(v, 32);
    return v;
}

__device__ inline float block_sum256(float v, float* lds4) {
    v = wave_sum64(v);
    const int w = threadIdx.x >> 6;
    __syncthreads();
    if ((threadIdx.x & 63) == 0) lds4[w] = v;
    __syncthreads();
    return lds4[0] + lds4[1] + lds4[2] + lds4[3];
}

// softcap+exp, branchless: exp(50*tanh(s*SCALE/50)) = exp(50 - 100/(1+e^{2x}))
__device__ __forceinline__ float softcap_exp(float s_raw) {
    const float K1 = 0.08838834764831845f * 0.04f;     // SCALE * 2/50
    float u = __expf(s_raw * K1);
    return __expf(50.f - 100.f * __builtin_amdgcn_rcpf(1.f + u));
}

// typed 4-wide loads -> f32
__device__ __forceinline__ void ld4f(const float* p, float v[4]) {
    float4 a = *(const float4*)p;
    v[0] = a.x; v[1] = a.y; v[2] = a.z; v[3] = a.w;
}
__device__ __forceinline__ void ld4f(const __bf16* p, float v[4]) {
    bf16x4 a = *(const bf16x4*)p;
    v[0] = (float)a[0]; v[1] = (float)a[1]; v[2] = (float)a[2]; v[3] = (float)a[3];
}

// ---------------------------------------------------------------- weight convert: f32 [K][N] -> bf16 [N][K]
__global__ void transpose_cvt(const float* __restrict__ src, __bf16* __restrict__ dst,
                              int K, int N) {
    __shared__ float tile[32][33];
    const int tx = threadIdx.x, ty = threadIdx.y;
    const int n0 = blockIdx.x * 32, k0 = blockIdx.y * 32;
    #pragma unroll
    for (int i = 0; i < 4; ++i)
        tile[ty + i * 8][tx] = src[(size_t)(k0 + ty + i * 8) * N + n0 + tx];
    __syncthreads();
    #pragma unroll
    for (int i = 0; i < 4; ++i)
        dst[(size_t)(n0 + ty + i * 8) * K + k0 + tx] = (__bf16)tile[tx][ty + i * 8];
}

// gate_up variant: 16-row blocks -> gate col j at row (j&~15)*2+(j&15), up at +16.
__global__ void transpose_cvt_gu(const float* __restrict__ src, __bf16* __restrict__ dst,
                                 int K, int N) {
    __shared__ float tile[32][33];
    const int tx = threadIdx.x, ty = threadIdx.y;
    const int n0 = blockIdx.x * 32, k0 = blockIdx.y * 32;
    #pragma unroll
    for (int i = 0; i < 4; ++i)
        tile[ty + i * 8][tx] = src[(size_t)(k0 + ty + i * 8) * N + n0 + tx];
    __syncthreads();
    #pragma unroll
    for (int i = 0; i < 4; ++i) {
        int n = n0 + ty + i * 8;
        int rI;
        if (n < 8192) rI = ((n & ~15) << 1) + (n & 15);
        else { int u = n - 8192; rI = ((u & ~15) << 1) + 16 + (u & 15); }
        dst[(size_t)rI * K + k0 + tx] = (__bf16)tile[tx][ty + i * 8];
    }
}

// bf16 [R][C] -> [C][R], per head (grid.z)
__global__ void transpose_bf16_k(const __bf16* __restrict__ src0, __bf16* __restrict__ dst0,
                                 int R, int C) {
    __shared__ __bf16 tile[32][34];
    const int z = blockIdx.z;
    const __bf16* src = src0 + (size_t)z * R * C;
    __bf16* dst = dst0 + (size_t)z * R * C;
    const int tx = threadIdx.x, ty = threadIdx.y;
    const int c0 = blockIdx.x * 32, r0 = blockIdx.y * 32;
    #pragma unroll
    for (int i = 0; i < 4; ++i)
        tile[ty + i * 8][tx] = src[(size_t)(r0 + ty + i * 8) * C + c0 + tx];
    __syncthreads();
    #pragma unroll
    for (int i = 0; i < 4; ++i)
        dst[(size_t)(c0 + ty + i * 8) * R + r0 + tx] = tile[tx][ty + i * 8];
}

// ---------------------------------------------------------------- embedding gather
__global__ __launch_bounds__(256) void embed_k(const float* __restrict__ emb,
                                               const int* __restrict__ ids,
                                               float* __restrict__ x) {
    const int row = blockIdx.x, t = threadIdx.x;
    const int id = ids[row];
    const size_t src = (size_t)id * DMODEL, dst = (size_t)row * DMODEL;
    const float sc = 45.2548339959390f;   // sqrt(2048)
    float4 a = *(const float4*)&emb[src + t * 4];
    float4 b = *(const float4*)&emb[src + t * 4 + 1024];
    a.x *= sc; a.y *= sc; a.z *= sc; a.w *= sc;
    b.x *= sc; b.y *= sc; b.z *= sc; b.w *= sc;
    *(float4*)&x[dst + t * 4] = a;
    *(float4*)&x[dst + t * 4 + 1024] = b;
}

// ---------------------------------------------------------------- segment-id scan
__global__ __launch_bounds__(256) void seg_scan(const int* __restrict__ pos,
                                                int* __restrict__ seg) {
    __shared__ int wsum[4];
    const int b = blockIdx.x, t = threadIdx.x;
    const int lane = t & 63, wv = t >> 6;
    const int base = b * SEQ;
    int f[8]; int loc = 0;
    #pragma unroll
    for (int i = 0; i < 8; ++i) {
        int s = t * 8 + i;
        int fl = (s > 0) ? (pos[base + s] <= pos[base + s - 1]) : 0;
        f[i] = fl; loc += fl;
    }
    int sc = loc;
    for (int o = 1; o < 64; o <<= 1) { int n = __shfl_up(sc, o); if (lane >= o) sc += n; }
    if (lane == 63) wsum[wv] = sc;
    __syncthreads();
    int wb = 0;
    for (int i = 0; i < wv; ++i) wb += wsum[i];
    int run = wb + sc - loc + 1;
    #pragma unroll
    for (int i = 0; i < 8; ++i) { run += f[i]; seg[base + t * 8 + i] = run; }
}

// ---------------------------------------------------------------- fused residual add + rmsnorm
template<int MODE, int NH, typename HT>
__global__ __launch_bounds__(256) void fused_norm_k(
        float* __restrict__ x, const HT* __restrict__ hA, const HT* __restrict__ hB,
        const float* __restrict__ wA, const float* __restrict__ wB,
        __bf16* __restrict__ outb, float* __restrict__ outf) {
    __shared__ float lds4[4];
    const int row = blockIdx.x, t = threadIdx.x;
    const size_t base = (size_t)row * DMODEL;
    const int c0 = t * 4, c1 = t * 4 + 1024;
    float v[8];
    if constexpr (MODE == 0) {
        float4 a = *(const float4*)&x[base + c0];
        float4 b = *(const float4*)&x[base + c1];
        v[0]=a.x; v[1]=a.y; v[2]=a.z; v[3]=a.w;
        v[4]=b.x; v[5]=b.y; v[6]=b.z; v[7]=b.w;
    } else {
        float hv[8];
        ld4f(hA + base + c0, &hv[0]);
        ld4f(hA + base + c1, &hv[4]);
        if constexpr (NH == 2) {
            float gv[8];
            ld4f(hB + base + c0, &gv[0]);
            ld4f(hB + base + c1, &gv[4]);
            #pragma unroll
            for (int i = 0; i < 8; ++i) hv[i] += gv[i];
        }
        float ss = 0.f;
        #pragma unroll
        for (int i = 0; i < 8; ++i) ss += hv[i] * hv[i];
        float tot = block_sum256(ss, lds4);
        float rs = rsqrtf(tot * (1.f / DMODEL) + 1e-6f);
        float4 xa = *(const float4*)&x[base + c0];
        float4 xb = *(const float4*)&x[base + c1];
        float xv[8] = {xa.x, xa.y, xa.z, xa.w, xb.x, xb.y, xb.z, xb.w};
        #pragma unroll
        for (int i = 0; i < 8; ++i) {
            int c = (i < 4) ? c0 + i : c1 + i - 4;
            v[i] = xv[i] + hv[i] * rs * (1.f + wA[c]);
        }
        float4 o0 = {v[0], v[1], v[2], v[3]}, o1 = {v[4], v[5], v[6], v[7]};
        *(float4*)&x[base + c0] = o0;
        *(float4*)&x[base + c1] = o1;
    }
    float ss2 = 0.f;
    #pragma unroll
    for (int i = 0; i < 8; ++i) ss2 += v[i] * v[i];
    float tot2 = block_sum256(ss2, lds4);
    float rs2 = rsqrtf(tot2 * (1.f / DMODEL) + 1e-6f);
    #pragma unroll
    for (int i = 0; i < 8; ++i) {
        int c = (i < 4) ? c0 + i : c1 + i - 4;
        float o = v[i] * rs2 * (1.f + wB[c]);
        if constexpr (MODE == 2) outf[base + c] = o;
        else outb[base + c] = (__bf16)o;
    }
}

// ---------------------------------------------------------------- 256^2 GEMM, m201-faithful 4-phase K-loop:
// per phase { reads BEFORE barrier -> stage issues -> s_barrier ->
// lgkmcnt(0)+sched_barrier -> setprio(1) 16xMFMA setprio(0) -> s_barrier }.
template<int MH, int NH>
__device__ __forceinline__ void quad(f32x4 (&acc)[8][4], const bf16x8 (&af)[4][2],
                                     const bf16x8 (&bfr)[2][2]) {
    #pragma unroll
    for (int mq = 0; mq < 4; ++mq)
        #pragma unroll
        for (int nq = 0; nq < 2; ++nq)
            #pragma unroll
            for (int ks = 0; ks < 2; ++ks)
                acc[MH*4+mq][NH*2+nq] = mfma16(af[mq][ks], bfr[nq][ks], acc[MH*4+mq][NH*2+nq]);
}

template<typename OutT, int GELU>
__global__ __launch_bounds__(512, 2) void gemm8p(const __bf16* __restrict__ A,
                                                 const __bf16* __restrict__ Bw,
                                                 OutT* __restrict__ C,
                                                 int M, int N, int Ksub, int lda, int ldb) {
    __shared__ __bf16 lds[65536];   // 128 KiB: [buf][A|B][half][sub][64][64]
    const int z = blockIdx.z;
    A += (size_t)z * Ksub;
    Bw += (size_t)z * Ksub;
    C += (size_t)z * M * N;

    // XCD swizzle then grouped (GROUP_M=8) tile map
    const int nx = gridDim.x;
    const int ny = gridDim.y;
    const int nwg = nx * ny;
    const int orig = blockIdx.y * nx + blockIdx.x;
    const int wg = ((nwg & 7) == 0) ? ((orig & 7) * (nwg >> 3) + (orig >> 3)) : orig;
    const int gsize = 8 * nx;
    const int gid = wg / gsize;
    const int first_m = gid * 8;
    const int rows = min(8, ny - first_m);
    const int loc = wg - gid * gsize;
    const int bm = (first_m + loc % rows) * 256;
    const int bn = (loc / rows) * 256;

    const int t = threadIdx.x;
    const int w = t >> 6, lane = t & 63;
    const int wm = w >> 2, wn = w & 3;
    const int lg = lane >> 4, lr = lane & 15;

    const int rS = t >> 3, sS = t & 7;          // unit-staging: row 0..63, slot 0..7
    const int colS = ((sS ^ (rS & 7)) << 3);
    const __bf16* Ag = A + (size_t)(bm + rS) * lda + colS;
    const __bf16* Bg = Bw + (size_t)(bn + rS) * ldb + colS;
    const int nt = Ksub >> 6;

// one gload per thread = one 64x64 unit (8 KB).  h = half (128 rows), s = sub (64 rows)
#define STAGE_AU(kt, h, s) { \
        const __bf16* g_ = Ag + (size_t)((h) * 128 + (s) * 64) * lda + (size_t)(kt) * 64; \
        gload16(g_, &lds[(((kt) & 1) << 15) + (h) * 8192 + (s) * 4096 + t * 8]); }
#define STAGE_BU(kt, h, s) { \
        const __bf16* g_ = Bg + (size_t)((h) * 128 + (s) * 64) * ldb + (size_t)(kt) * 64; \
        gload16(g_, &lds[(((kt) & 1) << 15) + 16384 + (h) * 8192 + (s) * 4096 + t * 8]); }

    f32x4 acc[8][4] = {};
    bf16x8 af[4][2], bf0[2][2], bf1[2][2];

    const int swz = (lr & 7) << 3;
    const int aBase = wm * 8192;
    const int bBase = 16384 + (wn >> 1) * 8192;
    const int bRow0 = (wn & 1) * 64;
    const int lo0 = (lg * 8) ^ swz;
    const int lo1 = (32 + lg * 8) ^ swz;

#define RD_A(bufv, rowoff) { \
        _Pragma("unroll") \
        for (int mq = 0; mq < 4; ++mq) { \
            const int rb_ = (bufv) + aBase + ((rowoff) + mq * 16 + lr) * 64; \
            af[mq][0] = *(const bf16x8*)&lds[rb_ + lo0]; \
            af[mq][1] = *(const bf16x8*)&lds[rb_ + lo1]; } }
#define RD_B0(bufv) { \
        _Pragma("unroll") \
        for (int nq = 0; nq < 2; ++nq) { \
            const int rb_ = (bufv) + bBase + (bRow0 + nq * 16 + lr) * 64; \
            bf0[nq][0] = *(const bf16x8*)&lds[rb_ + lo0]; \
            bf0[nq][1] = *(const bf16x8*)&lds[rb_ + lo1]; } }
#define RD_B1(bufv) { \
        _Pragma("unroll") \
        for (int nq = 0; nq < 2; ++nq) { \
            const int rb_ = (bufv) + bBase + (bRow0 + 32 + nq * 16 + lr) * 64; \
            bf1[nq][0] = *(const bf16x8*)&lds[rb_ + lo0]; \
            bf1[nq][1] = *(const bf16x8*)&lds[rb_ + lo1]; } }

// m201 phase tail: barrier; lgkmcnt(0); sched fence; prio-wrapped MFMA; barrier
#define PHASE_TAIL(...) \
        __builtin_amdgcn_s_barrier(); \
        asm volatile("s_waitcnt lgkmcnt(0)" ::: "memory"); \
        __builtin_amdgcn_sched_barrier(0); \
        __builtin_amdgcn_s_setprio(1); \
        __VA_ARGS__; \
        __builtin_amdgcn_s_setprio(0); \
        __builtin_amdgcn_s_barrier();

    // prologue: stage tiles 0 and 1 fully; wait tile 0 landed
    STAGE_BU(0, 0, 0); STAGE_BU(0, 0, 1); STAGE_BU(0, 1, 0); STAGE_BU(0, 1, 1);
    STAGE_AU(0, 0, 0); STAGE_AU(0, 1, 0); STAGE_AU(0, 0, 1); STAGE_AU(0, 1, 1);
    STAGE_BU(1, 0, 0); STAGE_BU(1, 0, 1); STAGE_BU(1, 1, 0); STAGE_BU(1, 1, 1);
    STAGE_AU(1, 0, 0); STAGE_AU(1, 1, 0); STAGE_AU(1, 0, 1); STAGE_AU(1, 1, 1);
    if (nt > 1) { asm volatile("s_waitcnt vmcnt(8)" ::: "memory"); }
    else        { asm volatile("s_waitcnt vmcnt(0)" ::: "memory"); }
    __builtin_amdgcn_s_barrier();

    for (int kt = 0; kt < nt; ++kt) {
        const int buf = (kt & 1) << 15;
        const bool p1 = (kt + 1 < nt), p2 = (kt + 2 < nt);
        // ---- phase A: reads A-suba + B0 (last reader of A-suba)
        RD_A(buf, 0); RD_B0(buf);
        PHASE_TAIL((quad<0, 0>(acc, af, bf0)));
        // ---- phase B: reads B1 (last reader of B units); stage A-suba(t+2)
        RD_B1(buf);
        if (p2) { STAGE_AU(kt + 2, 0, 0); STAGE_AU(kt + 2, 1, 0); }
        PHASE_TAIL((quad<0, 1>(acc, af, bf1)));
        // ---- phase C: reads A-subb (last reader); stage B(t+2) x4
        RD_A(buf, 64);
        if (p2) {
            STAGE_BU(kt + 2, 0, 0); STAGE_BU(kt + 2, 0, 1);
            STAGE_BU(kt + 2, 1, 0); STAGE_BU(kt + 2, 1, 1);
        }
        PHASE_TAIL((quad<1, 1>(acc, af, bf1)));
        // ---- phase D: stage A-subb(t+2); counted vmcnt -> tile t+1 landed
        if (p2) {
            STAGE_AU(kt + 2, 0, 1); STAGE_AU(kt + 2, 1, 1);
            asm volatile("s_waitcnt vmcnt(8)" ::: "memory");
        } else if (p1) {
            asm volatile("s_waitcnt vmcnt(0)" ::: "memory");
        }
        __builtin_amdgcn_s_barrier();
        __builtin_amdgcn_s_setprio(1);
        quad<1, 0>(acc, af, bf0);
        __builtin_amdgcn_s_setprio(0);
        __builtin_amdgcn_s_barrier();
    }
#undef STAGE_AU
#undef STAGE_BU
#undef RD_A
#undef RD_B0
#undef RD_B1
#undef PHASE_TAIL

    if constexpr (GELU) {
        const int nhalf = N >> 1;
        #pragma unroll
        for (int m = 0; m < 8; ++m)
            #pragma unroll
            for (int pp = 0; pp < 2; ++pp)
                #pragma unroll
                for (int r = 0; r < 4; ++r) {
                    float g = acc[m][2 * pp][r];
                    float u = acc[m][2 * pp + 1][r];
                    float a2 = 1.5957691216057308f * (g + 0.044715f * g * g * g);
                    float sig = __builtin_amdgcn_rcpf(1.f + __expf(-a2));
                    float res = g * sig * u;
                    const int row = bm + wm * 128 + m * 16 + lg * 4 + r;
                    const int col = (bn >> 1) + wn * 32 + pp * 16 + lr;
                    C[(size_t)row * nhalf + col] = (OutT)res;
                }
    } else {
        #pragma unroll
        for (int m = 0; m < 8; ++m)
            #pragma unroll
            for (int n = 0; n < 4; ++n)
                #pragma unroll
                for (int r = 0; r < 4; ++r) {
                    const int row = bm + wm * 128 + m * 16 + lg * 4 + r;
                    const int col = bn + wn * 64 + n * 16 + lr;
                    C[(size_t)row * N + col] = (OutT)acc[m][n][r];
                }
    }
}

// ---------------------------------------------------------------- QKV post (bf16 in): rmsnorm (q,k) + RoPE
__global__ __launch_bounds__(256) void qkv_post(const __bf16* __restrict__ qkv,
                                                const float* __restrict__ qnw,
                                                const float* __restrict__ knw,
                                                const int* __restrict__ posid,
                                                __bf16* __restrict__ qg,
                                                __bf16* __restrict__ kg,
                                                __bf16* __restrict__ vg) {
    const int slot = blockIdx.x * 4 + (threadIdx.x >> 6);
    const int lane = threadIdx.x & 63;
    const int token = slot >> 5, j = slot & 31;
    const int b = token >> 11, s = token & (SEQ - 1);
    int base;
    const float* nw = nullptr;
    if (j < 16)      { base = j * 128;                nw = qnw; }
    else if (j < 24) { base = 2048 + (j - 16) * 128;  nw = knw; }
    else             { base = 3072 + (j - 24) * 128; }
    float e0 = (float)qkv[(size_t)token * 4096 + base + lane];
    float e1 = (float)qkv[(size_t)token * 4096 + base + lane + 64];
    if (j < 24) {
        float ss = wave_sum64(e0 * e0 + e1 * e1);
        float rs = rsqrtf(ss * (1.f / 128.f) + 1e-6f);
        e0 *= rs * (1.f + nw[lane]);
        e1 *= rs * (1.f + nw[lane + 64]);
        float p = (float)posid[token];
        float inv = exp2f(-13.287712379549449f * ((float)lane * (1.f / 64.f)));
        float f = p * inv;
        float c = cosf(f), sn = sinf(f);
        float o0 = e0 * c - e1 * sn;
        float o1 = e1 * c + e0 * sn;
        e0 = o0; e1 = o1;
    }
    size_t dst; __bf16* out;
    if (j < 16)      { dst = ((size_t)(b * NHQ  + j)        * SEQ + s) * HDIM; out = qg; }
    else if (j < 24) { dst = ((size_t)(b * NHKV + (j - 16)) * SEQ + s) * HDIM; out = kg; }
    else             { dst = ((size_t)(b * NHKV + (j - 24)) * SEQ + s) * HDIM; out = vg; }
    out[dst + lane] = (__bf16)e0;
    out[dst + lane + 64] = (__bf16)e1;
}

// ---------------------------------------------------------------- flash attention, softcap, mask fast-path, named-reg prefetch
template<int SLIDING>
__global__ __launch_bounds__(256, 3) void attn_k(const __bf16* __restrict__ qg,
                                                 const __bf16* __restrict__ kg,
                                                 const __bf16* __restrict__ vtg,
                                                 const int* __restrict__ seg,
                                                 const int* __restrict__ amask,
                                                 __bf16* __restrict__ outg) {
    __shared__ __align__(16) __bf16 Ks[64][136];
    __shared__ __align__(16) __bf16 Vs[128][72];
    __shared__ __align__(16) __bf16 Ps[4][16][72];
    __shared__ int segq_s[64], segk_s[64], kmk_s[64];
    __shared__ int flag_s;
    const int bh = blockIdx.y;
    const int b = bh >> 4, h = bh & 15, kvh = h >> 1;
    const int qb = blockIdx.x * 64;
    const int t = threadIdx.x, w = t >> 6, lane = t & 63;
    const int lg = lane >> 4, lr = lane & 15;
    const int segbase = b * SEQ;

    const size_t qoff = ((size_t)(b * NHQ + h) * SEQ + qb + w * 16) * HDIM;
    bf16x8 qf[4];
    #pragma unroll
    for (int kk = 0; kk < 4; ++kk)
        qf[kk] = *(const bf16x8*)&qg[qoff + (size_t)lr * HDIM + kk * 32 + lg * 8];
    if (t < 64) segq_s[t] = seg[segbase + qb + t];

    const int sqmin = seg[segbase + qb], sqmax = seg[segbase + qb + 63];

    const int krow = t >> 4, kcol = (t & 15) * 8;
    const int vrow = t >> 3, vcol = (t & 7) * 8;
    const __bf16* kB = kg + ((size_t)(b * NHKV + kvh) * SEQ) * HDIM + (size_t)krow * HDIM + kcol;
    const __bf16* vB = vtg + ((size_t)(b * NHKV + kvh) * HDIM + vrow) * SEQ + vcol;

    auto chunk_active = [&](int kb) -> bool {
        if (SLIDING && (qb - kb < -318 || qb - kb > 319)) return false;
        int skmin = seg[segbase + kb], skmax = seg[segbase + kb + 63];
        return (skmax >= sqmin) && (skmin <= sqmax);
    };
    auto next_kb = [&](int kb) -> int {
        for (kb += 64; kb < SEQ; kb += 64)
            if (chunk_active(kb)) return kb;
        return SEQ;
    };

    int4 kr0, kr1, kr2, kr3, vr0, vr1, vr2, vr3;
#define LOADR(kb_) { \
        kr0 = *(const int4*)(kB + (size_t)(kb_) * HDIM); \
        kr1 = *(const int4*)(kB + (size_t)((kb_) + 16) * HDIM); \
        kr2 = *(const int4*)(kB + (size_t)((kb_) + 32) * HDIM); \
        kr3 = *(const int4*)(kB + (size_t)((kb_) + 48) * HDIM); \
        vr0 = *(const int4*)(vB + (kb_)); \
        vr1 = *(const int4*)(vB + (size_t)32 * SEQ + (kb_)); \
        vr2 = *(const int4*)(vB + (size_t)64 * SEQ + (kb_)); \
        vr3 = *(const int4*)(vB + (size_t)96 * SEQ + (kb_)); }

    f32x4 oacc[8] = {};
    float den[4] = {0.f, 0.f, 0.f, 0.f};

    int kb = chunk_active(0) ? 0 : next_kb(0);
    if (kb < SEQ) LOADR(kb);

    while (kb < SEQ) {
        const int nkb = next_kb(kb);
        __syncthreads();
        *(int4*)&Ks[krow     ][kcol] = kr0;
        *(int4*)&Ks[krow + 16][kcol] = kr1;
        *(int4*)&Ks[krow + 32][kcol] = kr2;
        *(int4*)&Ks[krow + 48][kcol] = kr3;
        *(int4*)&Vs[vrow     ][vcol] = vr0;
        *(int4*)&Vs[vrow + 32][vcol] = vr1;
        *(int4*)&Vs[vrow + 64][vcol] = vr2;
        *(int4*)&Vs[vrow + 96][vcol] = vr3;
        if (w == 0) {
            int m = amask[segbase + kb + lane];
            int sk = seg[segbase + kb + lane];
            kmk_s[lane] = m; segk_s[lane] = sk;
            bool allm = (__ballot(m != 0) == ~0ull);
            bool segu = __all(sk == sqmin) && (sqmin == sqmax);
            bool wall = !SLIDING || (qb - kb >= -193 && qb - kb <= 192);
            if (lane == 0) flag_s = (allm && segu && wall) ? 1 : 0;
        }
        __syncthreads();
        if (nkb < SEQ) LOADR(nkb);
        const bool fast = (flag_s != 0);

        #pragma unroll
        for (int n = 0; n < 4; ++n) {
            f32x4 sc = {};
            __builtin_amdgcn_s_setprio(1);
            #pragma unroll
            for (int kk = 0; kk < 4; ++kk) {
                bf16x8 bfr = *(const bf16x8*)&Ks[n * 16 + lr][kk * 32 + lg * 8];
                sc = mfma16(qf[kk], bfr, sc);
            }
            __builtin_amdgcn_s_setprio(0);
            if (fast) {
                #pragma unroll
                for (int r = 0; r < 4; ++r) {
                    int row = lg * 4 + r;
                    float p = softcap_exp(sc[r]);
                    den[r] += p;
                    Ps[w][row][n * 16 + lr] = (__bf16)p;
                }
            } else {
                #pragma unroll
                for (int r = 0; r < 4; ++r) {
                    int row = lg * 4 + r;
                    int qi = qb + w * 16 + row;
                    int ki = kb + n * 16 + lr;
                    bool ok = (kmk_s[n * 16 + lr] != 0) &&
                              (segq_s[w * 16 + row] == segk_s[n * 16 + lr]);
                    if (SLIDING) { int d = qi - ki; ok = ok && (d >= -256) && (d <= 255); }
                    float p = ok ? softcap_exp(sc[r]) : 0.f;
                    den[r] += p;
                    Ps[w][row][n * 16 + lr] = (__bf16)p;
                }
            }
        }
        __builtin_amdgcn_s_setprio(1);
        #pragma unroll
        for (int kk2 = 0; kk2 < 2; ++kk2) {
            bf16x8 pf = *(const bf16x8*)&Ps[w][lr][kk2 * 32 + lg * 8];
            #pragma unroll
            for (int n2 = 0; n2 < 8; ++n2) {
                bf16x8 vf = *(const bf16x8*)&Vs[n2 * 16 + lr][kk2 * 32 + lg * 8];
                oacc[n2] = mfma16(pf, vf, oacc[n2]);
            }
        }
        __builtin_amdgcn_s_setprio(0);
        kb = nkb;
    }
#undef LOADR
    #pragma unroll
    for (int r = 0; r < 4; ++r) {
        float v = den[r];
        v += __shfl_xor(v, 1); v += __shfl_xor(v, 2);
        v += __shfl_xor(v, 4); v += __shfl_xor(v, 8);
        den[r] = __builtin_amdgcn_rcpf(v);
    }
    #pragma unroll
    for (int n2 = 0; n2 < 8; ++n2)
        #pragma unroll
        for (int r = 0; r < 4; ++r) {
            int row = qb + w * 16 + lg * 4 + r;
            float val = oacc[n2][r] * den[r];
            outg[((size_t)(b * SEQ) + row) * DMODEL + h * HDIM + n2 * 16 + lr] = (__bf16)val;
        }
}

// ---------------------------------------------------------------- launch
extern "C" void kernel_launch(void* const* d_in, const int* in_sizes, int n_in,
                              void* d_out, int out_size, void* d_ws, size_t ws_size,
                              hipStream_t stream) {
    const float* embedw = (const float*)d_in[0];
    const float* wq   = (const float*)d_in[1];
    const float* wk   = (const float*)d_in[2];
    const float* wv   = (const float*)d_in[3];
    const float* wo   = (const float*)d_in[4];
    const float* qnw  = (const float*)d_in[5];
    const float* knw  = (const float*)d_in[6];
    const float* lnin = (const float*)d_in[7];
    const float* lnpa = (const float*)d_in[8];
    const float* lnpf = (const float*)d_in[9];
    const float* lnpff= (const float*)d_in[10];
    const float* wguW = (const float*)d_in[11];
    const float* wdnW = (const float*)d_in[12];
    const float* fnw  = (const float*)d_in[13];
    const int* ids    = (const int*)d_in[14];
    const int* amask  = (const int*)d_in[15];
    const int* posid  = (const int*)d_in[16];
    float* outp = (float*)d_out;

    char* ws = (char*)d_ws;
    size_t off = 0;
    auto A = [&](size_t b) -> char* {
        char* p = ws + off;
        off = (off + b + 255) & ~(size_t)255;
        return p;
    };
    __bf16* qkvwt = (__bf16*)A((size_t)4096 * 2048 * 2);
    __bf16* wot   = (__bf16*)A((size_t)2048 * 2048 * 2);
    __bf16* wgut  = (__bf16*)A((size_t)16384 * 2048 * 2);
    __bf16* wdnt  = (__bf16*)A((size_t)2048 * 8192 * 2);
    float*  x     = (float*)A((size_t)NTOK * DMODEL * 4);
    __bf16* hbuf  = (__bf16*)A((size_t)NTOK * DMODEL * 2);
    __bf16* qkvb  = (__bf16*)A((size_t)NTOK * 4096 * 2);
    __bf16* qbh   = (__bf16*)A((size_t)BATCH * NHQ  * SEQ * HDIM * 2);
    __bf16* kbh   = (__bf16*)A((size_t)BATCH * NHKV * SEQ * HDIM * 2);
    __bf16* vbh   = (__bf16*)A((size_t)BATCH * NHKV * SEQ * HDIM * 2);
    __bf16* vtbh  = (__bf16*)A((size_t)BATCH * NHKV * SEQ * HDIM * 2);
    __bf16* attnb = (__bf16*)A((size_t)NTOK * DMODEL * 2);
    __bf16* actb  = (__bf16*)A((size_t)NTOK * FFDIM * 2);
    __bf16* pbuf  = (__bf16*)A((size_t)2 * NTOK * DMODEL * 2);   // bf16 split-K partials
    int*    seg   = (int*)A((size_t)BATCH * SEQ * 4);
    if (off > ws_size) return;

    const dim3 tb(32, 8);
    seg_scan<<<BATCH, 256, 0, stream>>>(posid, seg);
    embed_k<<<NTOK, 256, 0, stream>>>(embedw, ids, x);
    fused_norm_k<0,1,float><<<NTOK, 256, 0, stream>>>(x, nullptr, nullptr, nullptr, lnin,
                                                      hbuf, nullptr);

    for (int l = 0; l < 2; ++l) {
        transpose_cvt<<<dim3(64, 64), tb, 0, stream>>>(wq + (size_t)l * 2048 * 2048,
            qkvwt, 2048, 2048);
        transpose_cvt<<<dim3(32, 64), tb, 0, stream>>>(wk + (size_t)l * 2048 * 1024,
            qkvwt + (size_t)2048 * 2048, 2048, 1024);
        transpose_cvt<<<dim3(32, 64), tb, 0, stream>>>(wv + (size_t)l * 2048 * 1024,
            qkvwt + (size_t)3072 * 2048, 2048, 1024);
        transpose_cvt<<<dim3(64, 64), tb, 0, stream>>>(wo + (size_t)l * 2048 * 2048,
            wot, 2048, 2048);
        transpose_cvt_gu<<<dim3(512, 64), tb, 0, stream>>>(wguW + (size_t)l * 2048 * 16384,
            wgut, 2048, 16384);
        transpose_cvt<<<dim3(64, 256), tb, 0, stream>>>(wdnW + (size_t)l * 8192 * 2048,
            wdnt, 8192, 2048);

        gemm8p<__bf16,0><<<dim3(16, 16, 1), 512, 0, stream>>>(hbuf, qkvwt, qkvb,
                                                              4096, 4096, 2048, 2048, 2048);
        qkv_post<<<32768, 256, 0, stream>>>(qkvb, qnw + l * 128, knw + l * 128, posid,
                                            qbh, kbh, vbh);
        transpose_bf16_k<<<dim3(4, 64, BATCH * NHKV), tb, 0, stream>>>(vbh, vtbh, SEQ, HDIM);
        if (l == 0)
            attn_k<1><<<dim3(SEQ / 64, BATCH * NHQ), 256, 0, stream>>>(qbh, kbh, vtbh, seg,
                                                                       amask, attnb);
        else
            attn_k<0><<<dim3(SEQ / 64, BATCH * NHQ), 256, 0, stream>>>(qbh, kbh, vtbh, seg,
                                                                       amask, attnb);
        // O projection: split-K=2 bf16 partials -> fused into norm
        gemm8p<__bf16,0><<<dim3(8, 16, 2), 512, 0, stream>>>(attnb, wot, pbuf,
                                                             4096, 2048, 1024, 2048, 2048);
        fused_norm_k<1,2,__bf16><<<NTOK, 256, 0, stream>>>(x, pbuf,
                                                           pbuf + (size_t)NTOK * DMODEL,
                                                           lnpa + l * 2048, lnpf + l * 2048,
                                                           hbuf, nullptr);
        // MLP: merged M=4096 gate_up with fused GELU -> actb; merged down split-K=2
        gemm8p<__bf16,1><<<dim3(64, 16, 1), 512, 0, stream>>>(hbuf, wgut, actb,
                                                              4096, 16384, 2048, 2048, 2048);
        gemm8p<__bf16,0><<<dim3(8, 16, 2), 512, 0, stream>>>(actb, wdnt, pbuf,
                                                             4096, 2048, 4096, 8192, 8192);
        if (l == 0)
            fused_norm_k<1,2,__bf16><<<NTOK, 256, 0, stream>>>(x, pbuf,
                                                               pbuf + (size_t)NTOK * DMODEL,
                                                               lnpff, lnin + 2048,
                                                               hbuf, nullptr);
        else
            fused_norm_k<2,2,__bf16><<<NTOK, 256, 0, stream>>>(x, pbuf,
                                                               pbuf + (size_t)NTOK * DMODEL,
                                                               lnpff + 2048, fnw,
                                                               nullptr, outp);
    }
}

// Round 14
// 1345.409 us; speedup vs baseline: 1.0465x; 1.0465x over previous
//
#include <hip/hip_runtime.h>
#include <cstdint>
#include <cstddef>

// ---------------------------------------------------------------- types
typedef __bf16 bf16x8 __attribute__((ext_vector_type(8)));
typedef __bf16 bf16x4 __attribute__((ext_vector_type(4)));
typedef float  f32x4  __attribute__((ext_vector_type(4)));

#define BATCH 2
#define SEQ   2048
#define DMODEL 2048
#define NHQ   16
#define NHKV  8
#define HDIM  128
#define FFDIM 8192
#define NTOK  4096          // BATCH*SEQ

__device__ __forceinline__ f32x4 mfma16(bf16x8 a, bf16x8 b, f32x4 c) {
    return __builtin_amdgcn_mfma_f32_16x16x32_bf16(a, b, c, 0, 0, 0);
}

__device__ __forceinline__ void gload16(const __bf16* g, __bf16* l) {
    __builtin_amdgcn_global_load_lds(
        (const __attribute__((address_space(1))) void*)g,
        (__attribute__((address_space(3))) void*)l, 16, 0, 0);
}

__device__ inline float wave_sum64(float v) {
    v += __shfl_xor(v, 1);  v += __shfl_xor(v, 2);  v += __shfl_xor(v, 4);
    v += __shfl_xor(v, 8);  v += __shfl_xor(v, 16); v += __shfl_xor(v, 32);
    return v;
}

__device__ inline float block_sum256(float v, float* lds4) {
    v = wave_sum64(v);
    const int w = threadIdx.x >> 6;
    __syncthreads();
    if ((threadIdx.x & 63) == 0) lds4[w] = v;
    __syncthreads();
    return lds4[0] + lds4[1] + lds4[2] + lds4[3];
}

// softcap+exp, branchless: exp(50*tanh(s*SCALE/50)) = exp(50 - 100/(1+e^{2x}))
__device__ __forceinline__ float softcap_exp(float s_raw) {
    const float K1 = 0.08838834764831845f * 0.04f;     // SCALE * 2/50
    float u = __expf(s_raw * K1);
    return __expf(50.f - 100.f * __builtin_amdgcn_rcpf(1.f + u));
}

// typed 4-wide loads -> f32
__device__ __forceinline__ void ld4f(const float* p, float v[4]) {
    float4 a = *(const float4*)p;
    v[0] = a.x; v[1] = a.y; v[2] = a.z; v[3] = a.w;
}
__device__ __forceinline__ void ld4f(const __bf16* p, float v[4]) {
    bf16x4 a = *(const bf16x4*)p;
    v[0] = (float)a[0]; v[1] = (float)a[1]; v[2] = (float)a[2]; v[3] = (float)a[3];
}

// ---------------------------------------------------------------- weight convert: f32 [K][N] -> bf16 [N][K]
__global__ void transpose_cvt(const float* __restrict__ src, __bf16* __restrict__ dst,
                              int K, int N) {
    __shared__ float tile[32][33];
    const int tx = threadIdx.x, ty = threadIdx.y;
    const int n0 = blockIdx.x * 32, k0 = blockIdx.y * 32;
    #pragma unroll
    for (int i = 0; i < 4; ++i)
        tile[ty + i * 8][tx] = src[(size_t)(k0 + ty + i * 8) * N + n0 + tx];
    __syncthreads();
    #pragma unroll
    for (int i = 0; i < 4; ++i)
        dst[(size_t)(n0 + ty + i * 8) * K + k0 + tx] = (__bf16)tile[tx][ty + i * 8];
}

// gate_up variant: 16-row blocks -> gate col j at row (j&~15)*2+(j&15), up at +16.
__global__ void transpose_cvt_gu(const float* __restrict__ src, __bf16* __restrict__ dst,
                                 int K, int N) {
    __shared__ float tile[32][33];
    const int tx = threadIdx.x, ty = threadIdx.y;
    const int n0 = blockIdx.x * 32, k0 = blockIdx.y * 32;
    #pragma unroll
    for (int i = 0; i < 4; ++i)
        tile[ty + i * 8][tx] = src[(size_t)(k0 + ty + i * 8) * N + n0 + tx];
    __syncthreads();
    #pragma unroll
    for (int i = 0; i < 4; ++i) {
        int n = n0 + ty + i * 8;
        int rI;
        if (n < 8192) rI = ((n & ~15) << 1) + (n & 15);
        else { int u = n - 8192; rI = ((u & ~15) << 1) + 16 + (u & 15); }
        dst[(size_t)rI * K + k0 + tx] = (__bf16)tile[tx][ty + i * 8];
    }
}

// bf16 [R][C] -> [C][R], per head (grid.z)
__global__ void transpose_bf16_k(const __bf16* __restrict__ src0, __bf16* __restrict__ dst0,
                                 int R, int C) {
    __shared__ __bf16 tile[32][34];
    const int z = blockIdx.z;
    const __bf16* src = src0 + (size_t)z * R * C;
    __bf16* dst = dst0 + (size_t)z * R * C;
    const int tx = threadIdx.x, ty = threadIdx.y;
    const int c0 = blockIdx.x * 32, r0 = blockIdx.y * 32;
    #pragma unroll
    for (int i = 0; i < 4; ++i)
        tile[ty + i * 8][tx] = src[(size_t)(r0 + ty + i * 8) * C + c0 + tx];
    __syncthreads();
    #pragma unroll
    for (int i = 0; i < 4; ++i)
        dst[(size_t)(c0 + ty + i * 8) * R + r0 + tx] = tile[tx][ty + i * 8];
}

// ---------------------------------------------------------------- embedding gather
__global__ __launch_bounds__(256) void embed_k(const float* __restrict__ emb,
                                               const int* __restrict__ ids,
                                               float* __restrict__ x) {
    const int row = blockIdx.x, t = threadIdx.x;
    const int id = ids[row];
    const size_t src = (size_t)id * DMODEL, dst = (size_t)row * DMODEL;
    const float sc = 45.2548339959390f;   // sqrt(2048)
    float4 a = *(const float4*)&emb[src + t * 4];
    float4 b = *(const float4*)&emb[src + t * 4 + 1024];
    a.x *= sc; a.y *= sc; a.z *= sc; a.w *= sc;
    b.x *= sc; b.y *= sc; b.z *= sc; b.w *= sc;
    *(float4*)&x[dst + t * 4] = a;
    *(float4*)&x[dst + t * 4 + 1024] = b;
}

// ---------------------------------------------------------------- segment-id scan
__global__ __launch_bounds__(256) void seg_scan(const int* __restrict__ pos,
                                                int* __restrict__ seg) {
    __shared__ int wsum[4];
    const int b = blockIdx.x, t = threadIdx.x;
    const int lane = t & 63, wv = t >> 6;
    const int base = b * SEQ;
    int f[8]; int loc = 0;
    #pragma unroll
    for (int i = 0; i < 8; ++i) {
        int s = t * 8 + i;
        int fl = (s > 0) ? (pos[base + s] <= pos[base + s - 1]) : 0;
        f[i] = fl; loc += fl;
    }
    int sc = loc;
    for (int o = 1; o < 64; o <<= 1) { int n = __shfl_up(sc, o); if (lane >= o) sc += n; }
    if (lane == 63) wsum[wv] = sc;
    __syncthreads();
    int wb = 0;
    for (int i = 0; i < wv; ++i) wb += wsum[i];
    int run = wb + sc - loc + 1;
    #pragma unroll
    for (int i = 0; i < 8; ++i) { run += f[i]; seg[base + t * 8 + i] = run; }
}

// ---------------------------------------------------------------- fused residual add + rmsnorm
template<int MODE, int NH, typename HT>
__global__ __launch_bounds__(256) void fused_norm_k(
        float* __restrict__ x, const HT* __restrict__ hA, const HT* __restrict__ hB,
        const float* __restrict__ wA, const float* __restrict__ wB,
        __bf16* __restrict__ outb, float* __restrict__ outf) {
    __shared__ float lds4[4];
    const int row = blockIdx.x, t = threadIdx.x;
    const size_t base = (size_t)row * DMODEL;
    const int c0 = t * 4, c1 = t * 4 + 1024;
    float v[8];
    if constexpr (MODE == 0) {
        float4 a = *(const float4*)&x[base + c0];
        float4 b = *(const float4*)&x[base + c1];
        v[0]=a.x; v[1]=a.y; v[2]=a.z; v[3]=a.w;
        v[4]=b.x; v[5]=b.y; v[6]=b.z; v[7]=b.w;
    } else {
        float hv[8];
        ld4f(hA + base + c0, &hv[0]);
        ld4f(hA + base + c1, &hv[4]);
        if constexpr (NH == 2) {
            float gv[8];
            ld4f(hB + base + c0, &gv[0]);
            ld4f(hB + base + c1, &gv[4]);
            #pragma unroll
            for (int i = 0; i < 8; ++i) hv[i] += gv[i];
        }
        float ss = 0.f;
        #pragma unroll
        for (int i = 0; i < 8; ++i) ss += hv[i] * hv[i];
        float tot = block_sum256(ss, lds4);
        float rs = rsqrtf(tot * (1.f / DMODEL) + 1e-6f);
        float4 xa = *(const float4*)&x[base + c0];
        float4 xb = *(const float4*)&x[base + c1];
        float xv[8] = {xa.x, xa.y, xa.z, xa.w, xb.x, xb.y, xb.z, xb.w};
        #pragma unroll
        for (int i = 0; i < 8; ++i) {
            int c = (i < 4) ? c0 + i : c1 + i - 4;
            v[i] = xv[i] + hv[i] * rs * (1.f + wA[c]);
        }
        float4 o0 = {v[0], v[1], v[2], v[3]}, o1 = {v[4], v[5], v[6], v[7]};
        *(float4*)&x[base + c0] = o0;
        *(float4*)&x[base + c1] = o1;
    }
    float ss2 = 0.f;
    #pragma unroll
    for (int i = 0; i < 8; ++i) ss2 += v[i] * v[i];
    float tot2 = block_sum256(ss2, lds4);
    float rs2 = rsqrtf(tot2 * (1.f / DMODEL) + 1e-6f);
    #pragma unroll
    for (int i = 0; i < 8; ++i) {
        int c = (i < 4) ? c0 + i : c1 + i - 4;
        float o = v[i] * rs2 * (1.f + wB[c]);
        if constexpr (MODE == 2) outf[base + c] = o;
        else outb[base + c] = (__bf16)o;
    }
}

// ---------------------------------------------------------------- 256^2 GEMM (round-11 open-region variant)
template<int MH, int NH>
__device__ __forceinline__ void quad(f32x4 (&acc)[8][4], const bf16x8 (&af)[4][2],
                                     const bf16x8 (&bfr)[2][2]) {
    #pragma unroll
    for (int mq = 0; mq < 4; ++mq)
        #pragma unroll
        for (int nq = 0; nq < 2; ++nq)
            #pragma unroll
            for (int ks = 0; ks < 2; ++ks)
                acc[MH*4+mq][NH*2+nq] = mfma16(af[mq][ks], bfr[nq][ks], acc[MH*4+mq][NH*2+nq]);
}

template<typename OutT, int GELU>
__global__ __launch_bounds__(512, 2) void gemm8p(const __bf16* __restrict__ A,
                                                 const __bf16* __restrict__ Bw,
                                                 OutT* __restrict__ C,
                                                 int M, int N, int Ksub, int lda, int ldb) {
    __shared__ __bf16 lds[65536];   // 128 KiB: [buf][A|B][half][sub][64][64]
    const int z = blockIdx.z;
    A += (size_t)z * Ksub;
    Bw += (size_t)z * Ksub;
    C += (size_t)z * M * N;

    const int nx = gridDim.x;
    const int ny = gridDim.y;
    const int nwg = nx * ny;
    const int orig = blockIdx.y * nx + blockIdx.x;
    const int wg = ((nwg & 7) == 0) ? ((orig & 7) * (nwg >> 3) + (orig >> 3)) : orig;
    const int gsize = 8 * nx;
    const int gid = wg / gsize;
    const int first_m = gid * 8;
    const int rows = min(8, ny - first_m);
    const int loc = wg - gid * gsize;
    const int bm = (first_m + loc % rows) * 256;
    const int bn = (loc / rows) * 256;

    const int t = threadIdx.x;
    const int w = t >> 6, lane = t & 63;
    const int wm = w >> 2, wn = w & 3;
    const int lg = lane >> 4, lr = lane & 15;

    const int rS = t >> 3, sS = t & 7;
    const int colS = ((sS ^ (rS & 7)) << 3);
    const __bf16* Ag = A + (size_t)(bm + rS) * lda + colS;
    const __bf16* Bg = Bw + (size_t)(bn + rS) * ldb + colS;
    const int nt = Ksub >> 6;

#define STAGE_AU(kt, h, s) { \
        const __bf16* g_ = Ag + (size_t)((h) * 128 + (s) * 64) * lda + (size_t)(kt) * 64; \
        gload16(g_, &lds[(((kt) & 1) << 15) + (h) * 8192 + (s) * 4096 + t * 8]); }
#define STAGE_BU(kt, h, s) { \
        const __bf16* g_ = Bg + (size_t)((h) * 128 + (s) * 64) * ldb + (size_t)(kt) * 64; \
        gload16(g_, &lds[(((kt) & 1) << 15) + 16384 + (h) * 8192 + (s) * 4096 + t * 8]); }

    f32x4 acc[8][4] = {};
    bf16x8 af[4][2], bf0[2][2], bf1[2][2];

    const int swz = (lr & 7) << 3;
    const int aBase = wm * 8192;
    const int bBase = 16384 + (wn >> 1) * 8192;
    const int bRow0 = (wn & 1) * 64;
    const int lo0 = (lg * 8) ^ swz;
    const int lo1 = (32 + lg * 8) ^ swz;

#define RD_A(bufv, rowoff) { \
        _Pragma("unroll") \
        for (int mq = 0; mq < 4; ++mq) { \
            const int rb_ = (bufv) + aBase + ((rowoff) + mq * 16 + lr) * 64; \
            af[mq][0] = *(const bf16x8*)&lds[rb_ + lo0]; \
            af[mq][1] = *(const bf16x8*)&lds[rb_ + lo1]; } }
#define RD_B0(bufv) { \
        _Pragma("unroll") \
        for (int nq = 0; nq < 2; ++nq) { \
            const int rb_ = (bufv) + bBase + (bRow0 + nq * 16 + lr) * 64; \
            bf0[nq][0] = *(const bf16x8*)&lds[rb_ + lo0]; \
            bf0[nq][1] = *(const bf16x8*)&lds[rb_ + lo1]; } }
#define RD_B1(bufv) { \
        _Pragma("unroll") \
        for (int nq = 0; nq < 2; ++nq) { \
            const int rb_ = (bufv) + bBase + (bRow0 + 32 + nq * 16 + lr) * 64; \
            bf1[nq][0] = *(const bf16x8*)&lds[rb_ + lo0]; \
            bf1[nq][1] = *(const bf16x8*)&lds[rb_ + lo1]; } }

    // prologue: stage tile 0 in consumption-lead order (B x4, A-suba x2, A-subb x2)
    STAGE_BU(0, 0, 0); STAGE_BU(0, 0, 1); STAGE_BU(0, 1, 0); STAGE_BU(0, 1, 1);
    STAGE_AU(0, 0, 0); STAGE_AU(0, 1, 0); STAGE_AU(0, 0, 1); STAGE_AU(0, 1, 1);

    for (int kt = 0; kt < nt; ++kt) {
        const int buf = (kt & 1) << 15;
        const bool p1 = (kt + 1 < nt);
        // ---- ph0: stage B(t+1) half0; wait B(t)+A-suba(t); barrier; {reads ∥ Q00}
        if (p1) {
            STAGE_BU(kt + 1, 0, 0); STAGE_BU(kt + 1, 0, 1);
            asm volatile("s_waitcnt vmcnt(4)" ::: "memory");
        } else {
            asm volatile("s_waitcnt vmcnt(2)" ::: "memory");
        }
        __builtin_amdgcn_s_barrier();
        RD_A(buf, 0); RD_B0(buf);
        __builtin_amdgcn_s_setprio(1);
        quad<0,0>(acc, af, bf0);
        __builtin_amdgcn_s_setprio(0);
        // ---- ph1: stage B(t+1) half1; {RD_B1 ∥ Q01}
        if (p1) { STAGE_BU(kt + 1, 1, 0); STAGE_BU(kt + 1, 1, 1); }
        RD_B1(buf);
        __builtin_amdgcn_s_setprio(1);
        quad<0,1>(acc, af, bf1);
        __builtin_amdgcn_s_setprio(0);
        // ---- ph2: stage A-suba(t+1); wait A-subb(t); barrier; {RD_A64 ∥ Q11}
        if (p1) {
            STAGE_AU(kt + 1, 0, 0); STAGE_AU(kt + 1, 1, 0);
            asm volatile("s_waitcnt vmcnt(6)" ::: "memory");
        } else {
            asm volatile("s_waitcnt vmcnt(0)" ::: "memory");
        }
        __builtin_amdgcn_s_barrier();
        RD_A(buf, 64);
        __builtin_amdgcn_s_setprio(1);
        quad<1,1>(acc, af, bf1);
        __builtin_amdgcn_s_setprio(0);
        // ---- ph3: stage A-subb(t+1); Q10 (registers only)
        if (p1) { STAGE_AU(kt + 1, 0, 1); STAGE_AU(kt + 1, 1, 1); }
        __builtin_amdgcn_s_setprio(1);
        quad<1,0>(acc, af, bf0);
        __builtin_amdgcn_s_setprio(0);
    }
#undef STAGE_AU
#undef STAGE_BU
#undef RD_A
#undef RD_B0
#undef RD_B1

    if constexpr (GELU) {
        const int nhalf = N >> 1;
        #pragma unroll
        for (int m = 0; m < 8; ++m)
            #pragma unroll
            for (int pp = 0; pp < 2; ++pp)
                #pragma unroll
                for (int r = 0; r < 4; ++r) {
                    float g = acc[m][2 * pp][r];
                    float u = acc[m][2 * pp + 1][r];
                    float a2 = 1.5957691216057308f * (g + 0.044715f * g * g * g);
                    float sig = __builtin_amdgcn_rcpf(1.f + __expf(-a2));
                    float res = g * sig * u;
                    const int row = bm + wm * 128 + m * 16 + lg * 4 + r;
                    const int col = (bn >> 1) + wn * 32 + pp * 16 + lr;
                    C[(size_t)row * nhalf + col] = (OutT)res;
                }
    } else {
        #pragma unroll
        for (int m = 0; m < 8; ++m)
            #pragma unroll
            for (int n = 0; n < 4; ++n)
                #pragma unroll
                for (int r = 0; r < 4; ++r) {
                    const int row = bm + wm * 128 + m * 16 + lg * 4 + r;
                    const int col = bn + wn * 64 + n * 16 + lr;
                    C[(size_t)row * N + col] = (OutT)acc[m][n][r];
                }
    }
}

// ---------------------------------------------------------------- QKV post (bf16 in): rmsnorm (q,k) + RoPE
__global__ __launch_bounds__(256) void qkv_post(const __bf16* __restrict__ qkv,
                                                const float* __restrict__ qnw,
                                                const float* __restrict__ knw,
                                                const int* __restrict__ posid,
                                                __bf16* __restrict__ qg,
                                                __bf16* __restrict__ kg,
                                                __bf16* __restrict__ vg) {
    const int slot = blockIdx.x * 4 + (threadIdx.x >> 6);
    const int lane = threadIdx.x & 63;
    const int token = slot >> 5, j = slot & 31;
    const int b = token >> 11, s = token & (SEQ - 1);
    int base;
    const float* nw = nullptr;
    if (j < 16)      { base = j * 128;                nw = qnw; }
    else if (j < 24) { base = 2048 + (j - 16) * 128;  nw = knw; }
    else             { base = 3072 + (j - 24) * 128; }
    float e0 = (float)qkv[(size_t)token * 4096 + base + lane];
    float e1 = (float)qkv[(size_t)token * 4096 + base + lane + 64];
    if (j < 24) {
        float ss = wave_sum64(e0 * e0 + e1 * e1);
        float rs = rsqrtf(ss * (1.f / 128.f) + 1e-6f);
        e0 *= rs * (1.f + nw[lane]);
        e1 *= rs * (1.f + nw[lane + 64]);
        float p = (float)posid[token];
        float inv = exp2f(-13.287712379549449f * ((float)lane * (1.f / 64.f)));
        float f = p * inv;
        float c = cosf(f), sn = sinf(f);
        float o0 = e0 * c - e1 * sn;
        float o1 = e1 * c + e0 * sn;
        e0 = o0; e1 = o1;
    }
    size_t dst; __bf16* out;
    if (j < 16)      { dst = ((size_t)(b * NHQ  + j)        * SEQ + s) * HDIM; out = qg; }
    else if (j < 24) { dst = ((size_t)(b * NHKV + (j - 16)) * SEQ + s) * HDIM; out = kg; }
    else             { dst = ((size_t)(b * NHKV + (j - 24)) * SEQ + s) * HDIM; out = vg; }
    out[dst + lane] = (__bf16)e0;
    out[dst + lane + 64] = (__bf16)e1;
}

// ---------------------------------------------------------------- flash attention, QBLK=128 (8 waves), softcap,
// mask fast-path, named-reg prefetch
template<int SLIDING>
__global__ __launch_bounds__(512, 2) void attn_k(const __bf16* __restrict__ qg,
                                                 const __bf16* __restrict__ kg,
                                                 const __bf16* __restrict__ vtg,
                                                 const int* __restrict__ seg,
                                                 const int* __restrict__ amask,
                                                 __bf16* __restrict__ outg) {
    __shared__ __align__(16) __bf16 Ks[64][136];
    __shared__ __align__(16) __bf16 Vs[128][72];
    __shared__ __align__(16) __bf16 Ps[8][16][72];
    __shared__ int segq_s[128], segk_s[64], kmk_s[64];
    __shared__ int flag_s;
    const int bh = blockIdx.y;
    const int b = bh >> 4, h = bh & 15, kvh = h >> 1;
    const int qb = blockIdx.x * 128;
    const int t = threadIdx.x, w = t >> 6, lane = t & 63;
    const int lg = lane >> 4, lr = lane & 15;
    const int segbase = b * SEQ;

    const size_t qoff = ((size_t)(b * NHQ + h) * SEQ + qb + w * 16) * HDIM;
    bf16x8 qf[4];
    #pragma unroll
    for (int kk = 0; kk < 4; ++kk)
        qf[kk] = *(const bf16x8*)&qg[qoff + (size_t)lr * HDIM + kk * 32 + lg * 8];
    if (t < 128) segq_s[t] = seg[segbase + qb + t];

    const int sqmin = seg[segbase + qb], sqmax = seg[segbase + qb + 127];

    // staging (512 threads): K [64][128] as 2 int4/thread, V^T [128][64] as 2 int4/thread
    const int krow = t >> 4, kcol = (t & 15) * 8;     // krow 0..31
    const int vrow = t >> 3, vcol = (t & 7) * 8;      // vrow 0..63
    const __bf16* kB = kg + ((size_t)(b * NHKV + kvh) * SEQ) * HDIM + (size_t)krow * HDIM + kcol;
    const __bf16* vB = vtg + ((size_t)(b * NHKV + kvh) * HDIM + vrow) * SEQ + vcol;

    auto chunk_active = [&](int kb) -> bool {
        if (SLIDING && (qb - kb < -383 || qb - kb > 318)) return false;
        int skmin = seg[segbase + kb], skmax = seg[segbase + kb + 63];
        return (skmax >= sqmin) && (skmin <= sqmax);
    };
    auto next_kb = [&](int kb) -> int {
        for (kb += 64; kb < SEQ; kb += 64)
            if (chunk_active(kb)) return kb;
        return SEQ;
    };

    int4 kr0, kr1, vr0, vr1;
#define LOADR(kb_) { \
        kr0 = *(const int4*)(kB + (size_t)(kb_) * HDIM); \
        kr1 = *(const int4*)(kB + (size_t)((kb_) + 32) * HDIM); \
        vr0 = *(const int4*)(vB + (kb_)); \
        vr1 = *(const int4*)(vB + (size_t)64 * SEQ + (kb_)); }

    f32x4 oacc[8] = {};
    float den[4] = {0.f, 0.f, 0.f, 0.f};

    int kb = chunk_active(0) ? 0 : next_kb(0);
    if (kb < SEQ) LOADR(kb);

    while (kb < SEQ) {
        const int nkb = next_kb(kb);
        __syncthreads();
        *(int4*)&Ks[krow     ][kcol] = kr0;
        *(int4*)&Ks[krow + 32][kcol] = kr1;
        *(int4*)&Vs[vrow     ][vcol] = vr0;
        *(int4*)&Vs[vrow + 64][vcol] = vr1;
        if (w == 0) {
            int m = amask[segbase + kb + lane];
            int sk = seg[segbase + kb + lane];
            kmk_s[lane] = m; segk_s[lane] = sk;
            bool allm = (__ballot(m != 0) == ~0ull);
            bool segu = __all(sk == sqmin) && (sqmin == sqmax);
            bool wall = !SLIDING || (qb - kb >= -193 && qb - kb <= 128);
            if (lane == 0) flag_s = (allm && segu && wall) ? 1 : 0;
        }
        __syncthreads();
        if (nkb < SEQ) LOADR(nkb);
        const bool fast = (flag_s != 0);

        #pragma unroll
        for (int n = 0; n < 4; ++n) {
            f32x4 sc = {};
            __builtin_amdgcn_s_setprio(1);
            #pragma unroll
            for (int kk = 0; kk < 4; ++kk) {
                bf16x8 bfr = *(const bf16x8*)&Ks[n * 16 + lr][kk * 32 + lg * 8];
                sc = mfma16(qf[kk], bfr, sc);
            }
            __builtin_amdgcn_s_setprio(0);
            if (fast) {
                #pragma unroll
                for (int r = 0; r < 4; ++r) {
                    int row = lg * 4 + r;
                    float p = softcap_exp(sc[r]);
                    den[r] += p;
                    Ps[w][row][n * 16 + lr] = (__bf16)p;
                }
            } else {
                #pragma unroll
                for (int r = 0; r < 4; ++r) {
                    int row = lg * 4 + r;
                    int qi = qb + w * 16 + row;
                    int ki = kb + n * 16 + lr;
                    bool ok = (kmk_s[n * 16 + lr] != 0) &&
                              (segq_s[w * 16 + row] == segk_s[n * 16 + lr]);
                    if (SLIDING) { int d = qi - ki; ok = ok && (d >= -256) && (d <= 255); }
                    float p = ok ? softcap_exp(sc[r]) : 0.f;
                    den[r] += p;
                    Ps[w][row][n * 16 + lr] = (__bf16)p;
                }
            }
        }
        __builtin_amdgcn_s_setprio(1);
        #pragma unroll
        for (int kk2 = 0; kk2 < 2; ++kk2) {
            bf16x8 pf = *(const bf16x8*)&Ps[w][lr][kk2 * 32 + lg * 8];
            #pragma unroll
            for (int n2 = 0; n2 < 8; ++n2) {
                bf16x8 vf = *(const bf16x8*)&Vs[n2 * 16 + lr][kk2 * 32 + lg * 8];
                oacc[n2] = mfma16(pf, vf, oacc[n2]);
            }
        }
        __builtin_amdgcn_s_setprio(0);
        kb = nkb;
    }
#undef LOADR
    #pragma unroll
    for (int r = 0; r < 4; ++r) {
        float v = den[r];
        v += __shfl_xor(v, 1); v += __shfl_xor(v, 2);
        v += __shfl_xor(v, 4); v += __shfl_xor(v, 8);
        den[r] = __builtin_amdgcn_rcpf(v);
    }
    #pragma unroll
    for (int n2 = 0; n2 < 8; ++n2)
        #pragma unroll
        for (int r = 0; r < 4; ++r) {
            int row = qb + w * 16 + lg * 4 + r;
            float val = oacc[n2][r] * den[r];
            outg[((size_t)(b * SEQ) + row) * DMODEL + h * HDIM + n2 * 16 + lr] = (__bf16)val;
        }
}

// ---------------------------------------------------------------- launch
extern "C" void kernel_launch(void* const* d_in, const int* in_sizes, int n_in,
                              void* d_out, int out_size, void* d_ws, size_t ws_size,
                              hipStream_t stream) {
    const float* embedw = (const float*)d_in[0];
    const float* wq   = (const float*)d_in[1];
    const float* wk   = (const float*)d_in[2];
    const float* wv   = (const float*)d_in[3];
    const float* wo   = (const float*)d_in[4];
    const float* qnw  = (const float*)d_in[5];
    const float* knw  = (const float*)d_in[6];
    const float* lnin = (const float*)d_in[7];
    const float* lnpa = (const float*)d_in[8];
    const float* lnpf = (const float*)d_in[9];
    const float* lnpff= (const float*)d_in[10];
    const float* wguW = (const float*)d_in[11];
    const float* wdnW = (const float*)d_in[12];
    const float* fnw  = (const float*)d_in[13];
    const int* ids    = (const int*)d_in[14];
    const int* amask  = (const int*)d_in[15];
    const int* posid  = (const int*)d_in[16];
    float* outp = (float*)d_out;

    char* ws = (char*)d_ws;
    size_t off = 0;
    auto A = [&](size_t b) -> char* {
        char* p = ws + off;
        off = (off + b + 255) & ~(size_t)255;
        return p;
    };
    __bf16* qkvwt = (__bf16*)A((size_t)4096 * 2048 * 2);
    __bf16* wot   = (__bf16*)A((size_t)2048 * 2048 * 2);
    __bf16* wgut  = (__bf16*)A((size_t)16384 * 2048 * 2);
    __bf16* wdnt  = (__bf16*)A((size_t)2048 * 8192 * 2);
    float*  x     = (float*)A((size_t)NTOK * DMODEL * 4);
    __bf16* hbuf  = (__bf16*)A((size_t)NTOK * DMODEL * 2);
    __bf16* qkvb  = (__bf16*)A((size_t)NTOK * 4096 * 2);
    __bf16* qbh   = (__bf16*)A((size_t)BATCH * NHQ  * SEQ * HDIM * 2);
    __bf16* kbh   = (__bf16*)A((size_t)BATCH * NHKV * SEQ * HDIM * 2);
    __bf16* vbh   = (__bf16*)A((size_t)BATCH * NHKV * SEQ * HDIM * 2);
    __bf16* vtbh  = (__bf16*)A((size_t)BATCH * NHKV * SEQ * HDIM * 2);
    __bf16* attnb = (__bf16*)A((size_t)NTOK * DMODEL * 2);
    __bf16* actb  = (__bf16*)A((size_t)NTOK * FFDIM * 2);
    __bf16* pbuf  = (__bf16*)A((size_t)2 * NTOK * DMODEL * 2);   // bf16 split-K partials
    int*    seg   = (int*)A((size_t)BATCH * SEQ * 4);
    if (off > ws_size) return;

    const dim3 tb(32, 8);
    seg_scan<<<BATCH, 256, 0, stream>>>(posid, seg);
    embed_k<<<NTOK, 256, 0, stream>>>(embedw, ids, x);
    fused_norm_k<0,1,float><<<NTOK, 256, 0, stream>>>(x, nullptr, nullptr, nullptr, lnin,
                                                      hbuf, nullptr);

    for (int l = 0; l < 2; ++l) {
        transpose_cvt<<<dim3(64, 64), tb, 0, stream>>>(wq + (size_t)l * 2048 * 2048,
            qkvwt, 2048, 2048);
        transpose_cvt<<<dim3(32, 64), tb, 0, stream>>>(wk + (size_t)l * 2048 * 1024,
            qkvwt + (size_t)2048 * 2048, 2048, 1024);
        transpose_cvt<<<dim3(32, 64), tb, 0, stream>>>(wv + (size_t)l * 2048 * 1024,
            qkvwt + (size_t)3072 * 2048, 2048, 1024);
        transpose_cvt<<<dim3(64, 64), tb, 0, stream>>>(wo + (size_t)l * 2048 * 2048,
            wot, 2048, 2048);
        transpose_cvt_gu<<<dim3(512, 64), tb, 0, stream>>>(wguW + (size_t)l * 2048 * 16384,
            wgut, 2048, 16384);
        transpose_cvt<<<dim3(64, 256), tb, 0, stream>>>(wdnW + (size_t)l * 8192 * 2048,
            wdnt, 8192, 2048);

        gemm8p<__bf16,0><<<dim3(16, 16, 1), 512, 0, stream>>>(hbuf, qkvwt, qkvb,
                                                              4096, 4096, 2048, 2048, 2048);
        qkv_post<<<32768, 256, 0, stream>>>(qkvb, qnw + l * 128, knw + l * 128, posid,
                                            qbh, kbh, vbh);
        transpose_bf16_k<<<dim3(4, 64, BATCH * NHKV), tb, 0, stream>>>(vbh, vtbh, SEQ, HDIM);
        if (l == 0)
            attn_k<1><<<dim3(SEQ / 128, BATCH * NHQ), 512, 0, stream>>>(qbh, kbh, vtbh, seg,
                                                                        amask, attnb);
        else
            attn_k<0><<<dim3(SEQ / 128, BATCH * NHQ), 512, 0, stream>>>(qbh, kbh, vtbh, seg,
                                                                        amask, attnb);
        // O projection: split-K=2 bf16 partials -> fused into norm
        gemm8p<__bf16,0><<<dim3(8, 16, 2), 512, 0, stream>>>(attnb, wot, pbuf,
                                                             4096, 2048, 1024, 2048, 2048);
        fused_norm_k<1,2,__bf16><<<NTOK, 256, 0, stream>>>(x, pbuf,
                                                           pbuf + (size_t)NTOK * DMODEL,
                                                           lnpa + l * 2048, lnpf + l * 2048,
                                                           hbuf, nullptr);
        // MLP: merged M=4096 gate_up with fused GELU -> actb; merged down split-K=2
        gemm8p<__bf16,1><<<dim3(64, 16, 1), 512, 0, stream>>>(hbuf, wgut, actb,
                                                              4096, 16384, 2048, 2048, 2048);
        gemm8p<__bf16,0><<<dim3(8, 16, 2), 512, 0, stream>>>(actb, wdnt, pbuf,
                                                             4096, 2048, 4096, 8192, 8192);
        if (l == 0)
            fused_norm_k<1,2,__bf16><<<NTOK, 256, 0, stream>>>(x, pbuf,
                                                               pbuf + (size_t)NTOK * DMODEL,
                                                               lnpff, lnin + 2048,
                                                               hbuf, nullptr);
        else
            fused_norm_k<2,2,__bf16><<<NTOK, 256, 0, stream>>>(x, pbuf,
                                                               pbuf + (size_t)NTOK * DMODEL,
                                                               lnpff + 2048, fnw,
                                                               nullptr, outp);
    }
}